// Round 4
// baseline (363.536 us; speedup 1.0000x reference)
//
#include <hip/hip_runtime.h>
#include <hip/hip_bf16.h>

#define B_  32
#define T_  2048
#define DH_ 1024
#define DS_ 1024
#define A_  512
#define M_  (B_ * T_)   // 65536

typedef __attribute__((ext_vector_type(8))) short bf16x8;
typedef __attribute__((ext_vector_type(4))) float f32x4;

__device__ __forceinline__ unsigned short f2bf(float f) {
    union { float f; unsigned u; } v; v.f = f;
    unsigned r = 0x7FFFu + ((v.u >> 16) & 1u);
    return (unsigned short)((v.u + r) >> 16);
}
__device__ __forceinline__ float bflo(unsigned u) {
    union { unsigned u; float f; } v; v.u = u << 16; return v.f;
}
__device__ __forceinline__ float bfhi(unsigned u) {
    union { unsigned u; float f; } v; v.u = u & 0xFFFF0000u; return v.f;
}
__device__ __forceinline__ float fast_tanh(float x) {
    float cx = fminf(fmaxf(x, -9.f), 9.f);
    float e2 = __expf(2.f * cx);
    return (e2 - 1.f) / (e2 + 1.f);
}

// ---- zero e [M_] and c [B_*DH_] ------------------------------------------
__global__ void zero_kernel(float* __restrict__ e, float* __restrict__ c) {
    int i = blockIdx.x * blockDim.x + threadIdx.x;
    if (i < M_) e[i] = 0.f;
    int j = i - M_;
    if (j >= 0 && j < B_ * DH_) c[j] = 0.f;
}

// ---- U_t[a][k] = bf16(U_a[k][a]) -----------------------------------------
__global__ void prep_ut(const float* __restrict__ U, unsigned short* __restrict__ Ut) {
    int o = blockIdx.x * 256 + threadIdx.x;
    int a = o >> 10, k = o & (DH_ - 1);
    Ut[o] = f2bf(U[k * A_ + a]);
}

// ---- hb = bf16(h), 8 elems/thread ----------------------------------------
__global__ void conv_h(const float* __restrict__ h, unsigned int* __restrict__ hb) {
    size_t i = ((size_t)blockIdx.x * 256 + threadIdx.x) * 8;
    float4 a = *(const float4*)(h + i);
    float4 b = *(const float4*)(h + i + 4);
    uint4 o;
    o.x = (unsigned)f2bf(a.x) | ((unsigned)f2bf(a.y) << 16);
    o.y = (unsigned)f2bf(a.z) | ((unsigned)f2bf(a.w) << 16);
    o.z = (unsigned)f2bf(b.x) | ((unsigned)f2bf(b.y) << 16);
    o.w = (unsigned)f2bf(b.z) | ((unsigned)f2bf(b.w) << 16);
    *(uint4*)(hb + i / 2) = o;
}

// ---- Ws[b][a] = s[b,:] . W_a[:,a] ----------------------------------------
__global__ void ws_gemv(const float* __restrict__ s, const float* __restrict__ W,
                        float* __restrict__ Ws) {
    int idx = blockIdx.x * 256 + threadIdx.x;
    int b = idx >> 9, a = idx & (A_ - 1);
    const float* sp = s + b * DS_;
    float acc = 0.f;
#pragma unroll 4
    for (int k = 0; k < DS_; ++k) acc += sp[k] * W[k * A_ + a];
    Ws[idx] = acc;
}

// ---- main GEMM: 256x256 tile, BK=64, 8 waves, 2-phase counted template ---
// T3-min recipe: stage(buf^1) -> ds_read(buf) -> MFMA -> syncthreads.
// Both-sides granule swizzle (g ^= row&7): pre-swizzled global source,
// swizzled ds_read address. T5 setprio around MFMA clusters. XCD-chunked bid.
__global__ void __launch_bounds__(512, 2)
gemm_e_256(const unsigned short* __restrict__ hb,
           const unsigned short* __restrict__ Ut,
           const float* __restrict__ Ws, const float* __restrict__ va,
           float* __restrict__ e) {
    __shared__ unsigned short As[2][256][64];   // 64 KB
    __shared__ unsigned short Bs[2][256][64];   // 64 KB

    const int tid = threadIdx.x;
    // XCD-chunk swizzle: nwg = 512 (= 256 m-tiles x 2 n-tiles), 64 wg/XCD
    const int bid0 = blockIdx.x;
    const int bid = (bid0 & 7) * 64 + (bid0 >> 3);
    const int tn = bid & 1, tm = bid >> 1;      // n fast: A-panel pair same XCD
    const int rowBase = tm * 256, nBase = tn * 256;

    const int lane = tid & 63;
    const int wid = tid >> 6;                   // 8 waves: 2(M) x 4(N)
    const int wm = wid >> 2, wn = wid & 3;      // wave tile 128(m) x 64(n)
    const int lr = lane & 15, kg = lane >> 4;

    f32x4 acc[8][4];
#pragma unroll
    for (int i = 0; i < 8; ++i)
#pragma unroll
        for (int j = 0; j < 4; ++j) acc[i][j] = (f32x4){0.f, 0.f, 0.f, 0.f};

    // staging: 4 x 16B per thread per matrix per K-tile (32 KB each)
    auto stage = [&](int buf, int kt) {
        const int k0 = kt * 64;
#pragma unroll
        for (int j = 0; j < 4; ++j) {
            int b = j * 8192 + tid * 16;        // byte offset in 32 KB tile
            int r = b >> 7;                     // row 0..255
            int g = ((b >> 4) & 7) ^ (r & 7);   // swizzled source granule
            const unsigned short* ga = hb + (size_t)(rowBase + r) * DH_ + k0 + g * 8;
            __builtin_amdgcn_global_load_lds(
                (const __attribute__((address_space(1))) unsigned int*)ga,
                (__attribute__((address_space(3))) unsigned int*)(&As[buf][0][0] + (b >> 1)),
                16, 0, 0);
            const unsigned short* gb = Ut + (size_t)(nBase + r) * DH_ + k0 + g * 8;
            __builtin_amdgcn_global_load_lds(
                (const __attribute__((address_space(1))) unsigned int*)gb,
                (__attribute__((address_space(3))) unsigned int*)(&Bs[buf][0][0] + (b >> 1)),
                16, 0, 0);
        }
    };

    stage(0, 0);
    __syncthreads();

#pragma unroll 1
    for (int kt = 0; kt < DH_ / 64; ++kt) {
        const int buf = kt & 1;
        if (kt < DH_ / 64 - 1) stage(buf ^ 1, kt + 1);

#pragma unroll
        for (int kh = 0; kh < 2; ++kh) {
            bf16x8 bq[4];
#pragma unroll
            for (int nf = 0; nf < 4; ++nf) {
                int rb = wn * 64 + nf * 16 + lr;
                int gg = (kh * 4 + kg) ^ (rb & 7);
                bq[nf] = *(const bf16x8*)(&Bs[buf][0][0] + rb * 64 + gg * 8);
            }
#pragma unroll
            for (int mh = 0; mh < 2; ++mh) {
                bf16x8 aq[4];
#pragma unroll
                for (int mf = 0; mf < 4; ++mf) {
                    int ra = wm * 128 + mh * 64 + mf * 16 + lr;
                    int gg = (kh * 4 + kg) ^ (ra & 7);
                    aq[mf] = *(const bf16x8*)(&As[buf][0][0] + ra * 64 + gg * 8);
                }
                __builtin_amdgcn_s_setprio(1);
#pragma unroll
                for (int mf = 0; mf < 4; ++mf)
#pragma unroll
                    for (int nf = 0; nf < 4; ++nf)
                        acc[mh * 4 + mf][nf] = __builtin_amdgcn_mfma_f32_16x16x32_bf16(
                            aq[mf], bq[nf], acc[mh * 4 + mf][nf], 0, 0, 0);
                __builtin_amdgcn_s_setprio(0);
            }
        }
        __syncthreads();
    }

    // epilogue: e[row] += sum_a tanh(acc + Ws[b][a]) * v[a]
    const int bIdx = rowBase >> 11;             // 256-row tile within one batch
    const float* WsRow = Ws + bIdx * A_;
    float wsv[4], vav[4];
#pragma unroll
    for (int nf = 0; nf < 4; ++nf) {
        int a = nBase + wn * 64 + nf * 16 + lr;
        wsv[nf] = WsRow[a];
        vav[nf] = va[a];
    }
#pragma unroll
    for (int mi = 0; mi < 8; ++mi) {
#pragma unroll
        for (int j = 0; j < 4; ++j) {
            float ssum = 0.f;
#pragma unroll
            for (int nf = 0; nf < 4; ++nf) {
                float x = acc[mi][nf][j] + wsv[nf];
                ssum += fast_tanh(x) * vav[nf];
            }
            ssum += __shfl_xor(ssum, 1);
            ssum += __shfl_xor(ssum, 2);
            ssum += __shfl_xor(ssum, 4);
            ssum += __shfl_xor(ssum, 8);
            if (lr == 0) {
                int row = rowBase + wm * 128 + mi * 16 + kg * 4 + j;
                atomicAdd(&e[row], ssum);
            }
        }
    }
}

// ---- softmax over T per batch (in place on e) ----------------------------
__global__ void softmax_kernel(float* __restrict__ e) {
    __shared__ float red[8];
    const int b = blockIdx.x, tid = threadIdx.x;
    float* ep = e + b * T_;
    float4 v0 = ((float4*)ep)[tid * 2];
    float4 v1 = ((float4*)ep)[tid * 2 + 1];
    float m = fmaxf(fmaxf(fmaxf(v0.x, v0.y), fmaxf(v0.z, v0.w)),
                    fmaxf(fmaxf(v1.x, v1.y), fmaxf(v1.z, v1.w)));
#pragma unroll
    for (int off = 1; off < 64; off <<= 1) m = fmaxf(m, __shfl_xor(m, off));
    int wid = tid >> 6;
    if ((tid & 63) == 0) red[wid] = m;
    __syncthreads();
    m = fmaxf(fmaxf(red[0], red[1]), fmaxf(red[2], red[3]));
    v0.x = __expf(v0.x - m); v0.y = __expf(v0.y - m);
    v0.z = __expf(v0.z - m); v0.w = __expf(v0.w - m);
    v1.x = __expf(v1.x - m); v1.y = __expf(v1.y - m);
    v1.z = __expf(v1.z - m); v1.w = __expf(v1.w - m);
    float ssum = v0.x + v0.y + v0.z + v0.w + v1.x + v1.y + v1.z + v1.w;
#pragma unroll
    for (int off = 1; off < 64; off <<= 1) ssum += __shfl_xor(ssum, off);
    if ((tid & 63) == 0) red[4 + wid] = ssum;
    __syncthreads();
    float inv = 1.f / (red[4] + red[5] + red[6] + red[7]);
    v0.x *= inv; v0.y *= inv; v0.z *= inv; v0.w *= inv;
    v1.x *= inv; v1.y *= inv; v1.z *= inv; v1.w *= inv;
    ((float4*)ep)[tid * 2] = v0;
    ((float4*)ep)[tid * 2 + 1] = v1;
}

// ---- c[b][d] = sum_t a[b][t] * hb[b][t][d]  (bf16 h) ----------------------
__global__ void ctx_bf(const unsigned int* __restrict__ hb, const float* __restrict__ a,
                       float* __restrict__ c) {
    const int bid = blockIdx.x;
    const int b = bid >> 5, seg = bid & 31;
    const int tid = threadIdx.x;
    const int half = tid >> 7;                 // 0/1 interleaved t
    const int d0 = (tid & 127) * 8;
    const int t0 = seg * 64 + half;
    float acc[8] = {0.f, 0.f, 0.f, 0.f, 0.f, 0.f, 0.f, 0.f};
    const unsigned int* hp = hb + (((size_t)b * T_ + t0) * DH_ + d0) / 2;
    const float* ap = a + (size_t)b * T_ + t0;
#pragma unroll 4
    for (int t = 0; t < 64; t += 2) {
        float w = ap[t];
        uint4 v = *(const uint4*)(hp + (size_t)t * (DH_ / 2));
        acc[0] += w * bflo(v.x); acc[1] += w * bfhi(v.x);
        acc[2] += w * bflo(v.y); acc[3] += w * bfhi(v.y);
        acc[4] += w * bflo(v.z); acc[5] += w * bfhi(v.z);
        acc[6] += w * bflo(v.w); acc[7] += w * bfhi(v.w);
    }
    float* cp = c + (size_t)b * DH_ + d0;
#pragma unroll
    for (int j = 0; j < 8; ++j) atomicAdd(cp + j, acc[j]);
}

extern "C" void kernel_launch(void* const* d_in, const int* in_sizes, int n_in,
                              void* d_out, int out_size, void* d_ws, size_t ws_size,
                              hipStream_t stream) {
    const float* s   = (const float*)d_in[0];
    const float* h   = (const float*)d_in[1];
    const float* W_a = (const float*)d_in[2];
    const float* U_a = (const float*)d_in[3];
    const float* v_a = (const float*)d_in[4];
    float* c = (float*)d_out;

    // workspace layout (bytes): e | Ws | Ut | hb   (needs ~135.6 MB)
    const size_t off_Ws = (size_t)M_ * 4;
    const size_t off_Ut = off_Ws + (size_t)B_ * A_ * 4;
    const size_t off_hb = off_Ut + (size_t)A_ * DH_ * 2;

    float* e  = (float*)d_ws;
    float* Ws = (float*)((char*)d_ws + off_Ws);
    unsigned short* Ut = (unsigned short*)((char*)d_ws + off_Ut);
    unsigned int* hb = (unsigned int*)((char*)d_ws + off_hb);

    zero_kernel<<<(M_ + B_ * DH_ + 255) / 256, 256, 0, stream>>>(e, c);
    prep_ut<<<(A_ * DH_) / 256, 256, 0, stream>>>(U_a, Ut);
    ws_gemv<<<(B_ * A_) / 256, 256, 0, stream>>>(s, W_a, Ws);
    conv_h<<<(M_ * (size_t)DH_) / (256 * 8), 256, 0, stream>>>(h, hb);
    gemm_e_256<<<(M_ / 256) * (A_ / 256), 512, 0, stream>>>(
        (const unsigned short*)hb, Ut, Ws, v_a, e);
    softmax_kernel<<<B_, 256, 0, stream>>>(e);
    ctx_bf<<<B_ * 32, 256, 0, stream>>>(hb, e, c);
}

// Round 5
// 345.736 us; speedup vs baseline: 1.0515x; 1.0515x over previous
//
#include <hip/hip_runtime.h>
#include <hip/hip_bf16.h>

#define B_  32
#define T_  2048
#define DH_ 1024
#define DS_ 1024
#define A_  512
#define M_  (B_ * T_)   // 65536

typedef __attribute__((ext_vector_type(8))) short bf16x8;
typedef __attribute__((ext_vector_type(4))) float f32x4;

__device__ __forceinline__ unsigned short f2bf(float f) {
    union { float f; unsigned u; } v; v.f = f;
    unsigned r = 0x7FFFu + ((v.u >> 16) & 1u);
    return (unsigned short)((v.u + r) >> 16);
}
__device__ __forceinline__ float bflo(unsigned u) {
    union { unsigned u; float f; } v; v.u = u << 16; return v.f;
}
__device__ __forceinline__ float bfhi(unsigned u) {
    union { unsigned u; float f; } v; v.u = u & 0xFFFF0000u; return v.f;
}
__device__ __forceinline__ float fast_tanh(float x) {
    float cx = fminf(fmaxf(x, -9.f), 9.f);
    float e2 = __expf(2.f * cx);
    return (e2 - 1.f) / (e2 + 1.f);
}

// ---- zero e [M_] and c [B_*DH_] ------------------------------------------
__global__ void zero_kernel(float* __restrict__ e, float* __restrict__ c) {
    int i = blockIdx.x * blockDim.x + threadIdx.x;
    if (i < M_) e[i] = 0.f;
    int j = i - M_;
    if (j >= 0 && j < B_ * DH_) c[j] = 0.f;
}

// ---- U_t[a][k] = bf16(U_a[k][a]) -----------------------------------------
__global__ void prep_ut(const float* __restrict__ U, unsigned short* __restrict__ Ut) {
    int o = blockIdx.x * 256 + threadIdx.x;
    int a = o >> 10, k = o & (DH_ - 1);
    Ut[o] = f2bf(U[k * A_ + a]);
}

// ---- Ws[b][a] = s[b,:] . W_a[:,a] ----------------------------------------
__global__ void ws_gemv(const float* __restrict__ s, const float* __restrict__ W,
                        float* __restrict__ Ws) {
    int idx = blockIdx.x * 256 + threadIdx.x;
    int b = idx >> 9, a = idx & (A_ - 1);
    const float* sp = s + b * DS_;
    float acc = 0.f;
#pragma unroll 4
    for (int k = 0; k < DS_; ++k) acc += sp[k] * W[k * A_ + a];
    Ws[idx] = acc;
}

// ---- main GEMM: 256x256, BK=64, 8 waves, 2-phase; A reg-staged from f32 h
// (fused conversion; tn==0 blocks also emit hb bf16 for the ctx pass).
// B staged via global_load_lds with pre-swizzled source. Granule XOR swizzle
// (g ^= row&7) on both LDS write and read sides. XCD-chunked bid swizzle.
__global__ void __launch_bounds__(512, 1)
gemm_e_f(const float* __restrict__ h,
         const unsigned short* __restrict__ Ut,
         const float* __restrict__ Ws, const float* __restrict__ va,
         float* __restrict__ e, unsigned short* __restrict__ hb) {
    __shared__ unsigned short As[2][256][64];   // 64 KB
    __shared__ unsigned short Bs[2][256][64];   // 64 KB

    const int tid = threadIdx.x;
    // XCD-chunk swizzle: nwg = 512, 64 wg/XCD; tn-pair of each A-panel same XCD
    const int bid0 = blockIdx.x;
    const int bid = (bid0 & 7) * 64 + (bid0 >> 3);
    const int tn = bid & 1, tm = bid >> 1;
    const int rowBase = tm * 256, nBase = tn * 256;
    const bool writeHb = (tn == 0);

    const int lane = tid & 63;
    const int wid = tid >> 6;                   // 8 waves: 2(M) x 4(N)
    const int wm = wid >> 2, wn = wid & 3;      // wave tile 128(m) x 64(n)
    const int lr = lane & 15, kg = lane >> 4;

    // A-staging geometry: load j covers rows j*32 + (tid>>4), 16 B f32 at
    // col (tid&15)*4  -> per instruction 8 KB = 32 rows, 256 B/row contiguous
    const int aRow = tid >> 4;                  // 0..31
    const int aCol = (tid & 15) * 4;            // f32 col 0..60
    const int colb = (tid & 15) * 8;            // bf16 byte col in LDS row
    const int gsub = colb & 15;                 // 0 or 8 within granule

    f32x4 acc[8][4];
#pragma unroll
    for (int i = 0; i < 8; ++i)
#pragma unroll
        for (int j = 0; j < 4; ++j) acc[i][j] = (f32x4){0.f, 0.f, 0.f, 0.f};

    auto stageB = [&](int buf, int kt) {
        const int k0 = kt * 64;
#pragma unroll
        for (int j = 0; j < 4; ++j) {
            int b = j * 8192 + tid * 16;        // byte offset in 32 KB tile
            int r = b >> 7;                     // row 0..255
            int g = ((b >> 4) & 7) ^ (r & 7);   // swizzled source granule
            const unsigned short* gb = Ut + (size_t)(nBase + r) * DH_ + k0 + g * 8;
            __builtin_amdgcn_global_load_lds(
                (const __attribute__((address_space(1))) unsigned int*)gb,
                (__attribute__((address_space(3))) unsigned int*)(&Bs[buf][0][0] + (b >> 1)),
                16, 0, 0);
        }
    };

    auto loadA = [&](float4* areg, int kt) {
        const int k0 = kt * 64;
#pragma unroll
        for (int j = 0; j < 8; ++j) {
            int row = j * 32 + aRow;
            areg[j] = *(const float4*)(h + (size_t)(rowBase + row) * DH_ + k0 + aCol);
        }
    };

    auto writeA = [&](const float4* areg, int buf, int kt) {
        const int k0 = kt * 64;
#pragma unroll
        for (int j = 0; j < 8; ++j) {
            int row = j * 32 + aRow;
            ushort4 u;
            u.x = f2bf(areg[j].x); u.y = f2bf(areg[j].y);
            u.z = f2bf(areg[j].z); u.w = f2bf(areg[j].w);
            int g = (colb >> 4) ^ (row & 7);
            *(ushort4*)((char*)&As[buf][0][0] + row * 128 + g * 16 + gsub) = u;
            if (writeHb)
                *(ushort4*)(hb + (size_t)(rowBase + row) * DH_ + k0 + aCol) = u;
        }
    };

    float4 areg[8];
    stageB(0, 0);
    loadA(areg, 0);
    writeA(areg, 0, 0);
    __syncthreads();

#pragma unroll 1
    for (int kt = 0; kt < DH_ / 64; ++kt) {
        const int buf = kt & 1;
        const bool more = (kt < DH_ / 64 - 1);
        if (more) {
            stageB(buf ^ 1, kt + 1);
            loadA(areg, kt + 1);
        }

#pragma unroll
        for (int kh = 0; kh < 2; ++kh) {
            bf16x8 bq[4];
#pragma unroll
            for (int nf = 0; nf < 4; ++nf) {
                int rb = wn * 64 + nf * 16 + lr;
                int gg = (kh * 4 + kg) ^ (rb & 7);
                bq[nf] = *(const bf16x8*)(&Bs[buf][0][0] + rb * 64 + gg * 8);
            }
#pragma unroll
            for (int mh = 0; mh < 2; ++mh) {
                bf16x8 aq[4];
#pragma unroll
                for (int mf = 0; mf < 4; ++mf) {
                    int ra = wm * 128 + mh * 64 + mf * 16 + lr;
                    int gg = (kh * 4 + kg) ^ (ra & 7);
                    aq[mf] = *(const bf16x8*)(&As[buf][0][0] + ra * 64 + gg * 8);
                }
                __builtin_amdgcn_s_setprio(1);
#pragma unroll
                for (int mf = 0; mf < 4; ++mf)
#pragma unroll
                    for (int nf = 0; nf < 4; ++nf)
                        acc[mh * 4 + mf][nf] = __builtin_amdgcn_mfma_f32_16x16x32_bf16(
                            aq[mf], bq[nf], acc[mh * 4 + mf][nf], 0, 0, 0);
                __builtin_amdgcn_s_setprio(0);
            }
        }
        if (more) writeA(areg, buf ^ 1, kt + 1);
        __syncthreads();
    }

    // epilogue: e[row] += sum_a tanh(acc + Ws[b][a]) * v[a]
    const int bIdx = rowBase >> 11;
    const float* WsRow = Ws + bIdx * A_;
    float wsv[4], vav[4];
#pragma unroll
    for (int nf = 0; nf < 4; ++nf) {
        int a = nBase + wn * 64 + nf * 16 + lr;
        wsv[nf] = WsRow[a];
        vav[nf] = va[a];
    }
#pragma unroll
    for (int mi = 0; mi < 8; ++mi) {
#pragma unroll
        for (int j = 0; j < 4; ++j) {
            float ssum = 0.f;
#pragma unroll
            for (int nf = 0; nf < 4; ++nf) {
                float x = acc[mi][nf][j] + wsv[nf];
                ssum += fast_tanh(x) * vav[nf];
            }
            ssum += __shfl_xor(ssum, 1);
            ssum += __shfl_xor(ssum, 2);
            ssum += __shfl_xor(ssum, 4);
            ssum += __shfl_xor(ssum, 8);
            if (lr == 0) {
                int row = rowBase + wm * 128 + mi * 16 + kg * 4 + j;
                atomicAdd(&e[row], ssum);
            }
        }
    }
}

// ---- softmax over T per batch (in place on e) ----------------------------
__global__ void softmax_kernel(float* __restrict__ e) {
    __shared__ float red[8];
    const int b = blockIdx.x, tid = threadIdx.x;
    float* ep = e + b * T_;
    float4 v0 = ((float4*)ep)[tid * 2];
    float4 v1 = ((float4*)ep)[tid * 2 + 1];
    float m = fmaxf(fmaxf(fmaxf(v0.x, v0.y), fmaxf(v0.z, v0.w)),
                    fmaxf(fmaxf(v1.x, v1.y), fmaxf(v1.z, v1.w)));
#pragma unroll
    for (int off = 1; off < 64; off <<= 1) m = fmaxf(m, __shfl_xor(m, off));
    int wid = tid >> 6;
    if ((tid & 63) == 0) red[wid] = m;
    __syncthreads();
    m = fmaxf(fmaxf(red[0], red[1]), fmaxf(red[2], red[3]));
    v0.x = __expf(v0.x - m); v0.y = __expf(v0.y - m);
    v0.z = __expf(v0.z - m); v0.w = __expf(v0.w - m);
    v1.x = __expf(v1.x - m); v1.y = __expf(v1.y - m);
    v1.z = __expf(v1.z - m); v1.w = __expf(v1.w - m);
    float ssum = v0.x + v0.y + v0.z + v0.w + v1.x + v1.y + v1.z + v1.w;
#pragma unroll
    for (int off = 1; off < 64; off <<= 1) ssum += __shfl_xor(ssum, off);
    if ((tid & 63) == 0) red[4 + wid] = ssum;
    __syncthreads();
    float inv = 1.f / (red[4] + red[5] + red[6] + red[7]);
    v0.x *= inv; v0.y *= inv; v0.z *= inv; v0.w *= inv;
    v1.x *= inv; v1.y *= inv; v1.z *= inv; v1.w *= inv;
    ((float4*)ep)[tid * 2] = v0;
    ((float4*)ep)[tid * 2 + 1] = v1;
}

// ---- c[b][d] = sum_t a[b][t] * hb[b][t][d]  (bf16 h) ----------------------
__global__ void ctx_bf(const unsigned int* __restrict__ hb, const float* __restrict__ a,
                       float* __restrict__ c) {
    const int bid = blockIdx.x;
    const int b = bid >> 5, seg = bid & 31;
    const int tid = threadIdx.x;
    const int half = tid >> 7;                 // 0/1 interleaved t
    const int d0 = (tid & 127) * 8;
    const int t0 = seg * 64 + half;
    float acc[8] = {0.f, 0.f, 0.f, 0.f, 0.f, 0.f, 0.f, 0.f};
    const unsigned int* hp = hb + (((size_t)b * T_ + t0) * DH_ + d0) / 2;
    const float* ap = a + (size_t)b * T_ + t0;
#pragma unroll 4
    for (int t = 0; t < 64; t += 2) {
        float w = ap[t];
        uint4 v = *(const uint4*)(hp + (size_t)t * (DH_ / 2));
        acc[0] += w * bflo(v.x); acc[1] += w * bfhi(v.x);
        acc[2] += w * bflo(v.y); acc[3] += w * bfhi(v.y);
        acc[4] += w * bflo(v.z); acc[5] += w * bfhi(v.z);
        acc[6] += w * bflo(v.w); acc[7] += w * bfhi(v.w);
    }
    float* cp = c + (size_t)b * DH_ + d0;
#pragma unroll
    for (int j = 0; j < 8; ++j) atomicAdd(cp + j, acc[j]);
}

extern "C" void kernel_launch(void* const* d_in, const int* in_sizes, int n_in,
                              void* d_out, int out_size, void* d_ws, size_t ws_size,
                              hipStream_t stream) {
    const float* s   = (const float*)d_in[0];
    const float* h   = (const float*)d_in[1];
    const float* W_a = (const float*)d_in[2];
    const float* U_a = (const float*)d_in[3];
    const float* v_a = (const float*)d_in[4];
    float* c = (float*)d_out;

    // workspace layout (bytes): e | Ws | Ut | hb   (~129.3 MB)
    const size_t off_Ws = (size_t)M_ * 4;
    const size_t off_Ut = off_Ws + (size_t)B_ * A_ * 4;
    const size_t off_hb = off_Ut + (size_t)A_ * DH_ * 2;

    float* e  = (float*)d_ws;
    float* Ws = (float*)((char*)d_ws + off_Ws);
    unsigned short* Ut = (unsigned short*)((char*)d_ws + off_Ut);
    unsigned short* hb = (unsigned short*)((char*)d_ws + off_hb);

    zero_kernel<<<(M_ + B_ * DH_ + 255) / 256, 256, 0, stream>>>(e, c);
    prep_ut<<<(A_ * DH_) / 256, 256, 0, stream>>>(U_a, Ut);
    ws_gemv<<<(B_ * A_) / 256, 256, 0, stream>>>(s, W_a, Ws);
    gemm_e_f<<<(M_ / 256) * (A_ / 256), 512, 0, stream>>>(h, Ut, Ws, v_a, e, hb);
    softmax_kernel<<<B_, 256, 0, stream>>>(e);
    ctx_bf<<<B_ * 32, 256, 0, stream>>>((const unsigned int*)hb, e, c);
}